// Round 4
// baseline (449.098 us; speedup 1.0000x reference)
//
#include <hip/hip_runtime.h>
#include <hip/hip_bf16.h>

#define NROWS 8192
#define DDIM  256
#define INV_TEMP 20.0f   // 1/0.05

typedef __attribute__((ext_vector_type(8))) short bf16x8;
typedef __attribute__((ext_vector_type(4))) float f32x4;

// async global->LDS, 16B per lane. LDS dest = uniform base + lane*16.
__device__ static inline void async16(const void* g, void* l) {
    __builtin_amdgcn_global_load_lds(
        (const __attribute__((address_space(1))) void*)g,
        (__attribute__((address_space(3))) void*)l, 16, 0, 0);
}

// ---------------------------------------------------------------------------
// Kernel 1: per-row L2-normalize q and p (fp32), emit bf16 copies, fp32 diag.
// One wave per row, 4 rows (4 waves) per block. Block 0 also zeroes the
// completion tickets for the fused kernel (stream-ordered before it runs;
// re-zeroed every invocation so graph replays are safe).
// ---------------------------------------------------------------------------
__global__ __launch_bounds__(256) void norm_diag_kernel(
    const float* __restrict__ q, const float* __restrict__ p,
    unsigned short* __restrict__ qn, unsigned short* __restrict__ pn,
    float* __restrict__ diag, int* __restrict__ tickets)
{
    if (blockIdx.x == 0 && threadIdx.x < 66)
        tickets[threadIdx.x] = 0;          // [0..63] row tickets, [64] done

    const int row  = (blockIdx.x << 2) + (threadIdx.x >> 6);
    const int lane = threadIdx.x & 63;

    const float4 qv = ((const float4*)(q + (size_t)row * DDIM))[lane];
    const float4 pv = ((const float4*)(p + (size_t)row * DDIM))[lane];

    float sq = qv.x*qv.x + qv.y*qv.y + qv.z*qv.z + qv.w*qv.w;
    float sp = pv.x*pv.x + pv.y*pv.y + pv.z*pv.z + pv.w*pv.w;
    #pragma unroll
    for (int m = 1; m < 64; m <<= 1) {
        sq += __shfl_xor(sq, m);
        sp += __shfl_xor(sp, m);
    }
    const float qs = 1.0f / fmaxf(sqrtf(sq), 1e-8f);
    const float ps = 1.0f / fmaxf(sqrtf(sp), 1e-8f);

    const float qx = qv.x*qs, qy = qv.y*qs, qz = qv.z*qs, qw = qv.w*qs;
    const float px = pv.x*ps, py = pv.y*ps, pz = pv.z*ps, pw = pv.w*ps;

    float d = qx*px + qy*py + qz*pz + qw*pw;
    #pragma unroll
    for (int m = 1; m < 64; m <<= 1) d += __shfl_xor(d, m);
    if (lane == 0) diag[row] = d * INV_TEMP;

    union { unsigned short u16[4]; uint2 v; } uq, up;
    {
        __hip_bfloat16 b;
        b = __float2bfloat16(qx); uq.u16[0] = *(unsigned short*)&b;
        b = __float2bfloat16(qy); uq.u16[1] = *(unsigned short*)&b;
        b = __float2bfloat16(qz); uq.u16[2] = *(unsigned short*)&b;
        b = __float2bfloat16(qw); uq.u16[3] = *(unsigned short*)&b;
        b = __float2bfloat16(px); up.u16[0] = *(unsigned short*)&b;
        b = __float2bfloat16(py); up.u16[1] = *(unsigned short*)&b;
        b = __float2bfloat16(pz); up.u16[2] = *(unsigned short*)&b;
        b = __float2bfloat16(pw); up.u16[3] = *(unsigned short*)&b;
    }
    *(uint2*)(qn + (size_t)row * DDIM + lane * 4) = uq.v;
    *(uint2*)(pn + (size_t)row * DDIM + lane * 4) = up.v;
}

// ---------------------------------------------------------------------------
// Kernel 2: fused GEMM + sum-exp + rowsum + final loss (tickets).
// GEMM core identical to R3 (depth-2 prefetch, 3 LDS buffers, counted vmcnt,
// XCD-chunked swizzle). After writing its part[] slice, each block does a
// device-scope ACQ_REL ticket increment; the 64th block per rowblock becomes
// the finisher (identical summation order to the old rowsum_kernel), and the
// 64th finisher does the final 64-lane reduce (identical to final_kernel).
// No spinning -> safe under any dispatch order. Cross-XCD reads use
// agent-scope atomics; part cachelines are single-writer (512B-aligned).
// ---------------------------------------------------------------------------
__global__ __launch_bounds__(256, 3) void simexp_fused_kernel(
    const unsigned short* __restrict__ qn,
    const unsigned short* __restrict__ pn,
    float* __restrict__ part,       // [64 colblocks][8192 rows]
    const float* __restrict__ diag,
    float* __restrict__ loss_part,  // [64]
    int* __restrict__ tickets,      // [64] + done at [64]
    float* __restrict__ out)
{
    __shared__ unsigned char lds[3 * 16384];   // 3 x (As 8KB | Bs 8KB)

    const int tid  = threadIdx.x;
    const int lane = tid & 63;
    const int w    = tid >> 6;        // wave 0..3
    const int wr   = w >> 1;          // wave row (0..1)
    const int wc   = w & 1;           // wave col (0..1)
    const int quad = lane >> 4;
    const int l16  = lane & 15;

    // ---- XCD-chunked swizzle (bijective on 4096 blocks) ----
    const int L   = blockIdx.y * 64 + blockIdx.x;  // linear dispatch id
    const int xcd = L & 7;
    const int c   = L >> 3;
    const int rowblk = xcd * 8 + (c & 7);
    const int colblk = c >> 3;
    const int rowbase = rowblk * 128;
    const int colbase = colblk * 128;

    const unsigned short* gA0 = qn + (size_t)(rowbase + (2*w  )*16 + l16) * DDIM + quad * 8;
    const unsigned short* gA1 = qn + (size_t)(rowbase + (2*w+1)*16 + l16) * DDIM + quad * 8;
    const unsigned short* gB0 = pn + (size_t)(colbase + (2*w  )*16 + l16) * DDIM + quad * 8;
    const unsigned short* gB1 = pn + (size_t)(colbase + (2*w+1)*16 + l16) * DDIM + quad * 8;

    f32x4 acc[4][4];
    #pragma unroll
    for (int i = 0; i < 4; ++i)
        #pragma unroll
        for (int j = 0; j < 4; ++j) acc[i][j] = (f32x4)0.0f;

#define STAGE(buf, ks) do {                                             \
        unsigned char* _b = lds + (buf) * 16384;                        \
        async16(gA0 + (ks) * 32, _b +        (2*w    ) * 1024);         \
        async16(gA1 + (ks) * 32, _b +        (2*w + 1) * 1024);         \
        async16(gB0 + (ks) * 32, _b + 8192 + (2*w    ) * 1024);         \
        async16(gB1 + (ks) * 32, _b + 8192 + (2*w + 1) * 1024);         \
    } while (0)

    STAGE(0, 0);
    STAGE(1, 1);
    asm volatile("s_waitcnt vmcnt(4)" ::: "memory");   // stage(0) landed
    __builtin_amdgcn_s_barrier();
    asm volatile("" ::: "memory");

    #pragma unroll
    for (int ks = 0; ks < 8; ++ks) {
        if (ks < 6) STAGE((ks + 2) % 3, ks + 2);       // issue 2 tiles ahead

        const unsigned char* ba = lds + (ks % 3) * 16384;
        bf16x8 af[4], bf[4];
        #pragma unroll
        for (int i = 0; i < 4; ++i)
            af[i] = *(const bf16x8*)(ba + (wr*4 + i) * 1024 + quad * 256 + l16 * 16);
        #pragma unroll
        for (int j = 0; j < 4; ++j)
            bf[j] = *(const bf16x8*)(ba + 8192 + (wc*4 + j) * 1024 + quad * 256 + l16 * 16);

        #pragma unroll
        for (int i = 0; i < 4; ++i)
            #pragma unroll
            for (int j = 0; j < 4; ++j)
                acc[i][j] = __builtin_amdgcn_mfma_f32_16x16x32_bf16(
                    af[i], bf[j], acc[i][j], 0, 0, 0);

        if (ks < 7) {
            if (ks < 6) { asm volatile("s_waitcnt vmcnt(4)" ::: "memory"); }
            else        { asm volatile("s_waitcnt vmcnt(0)" ::: "memory"); }
            __builtin_amdgcn_s_barrier();
            asm volatile("" ::: "memory");
        }
    }
#undef STAGE

    // epilogue: exp + partial rowsums -------------------------------------
    __syncthreads();                   // done with staged tiles; reuse LDS
    float* red = (float*)lds;          // 256 floats: [wc][128 rows]

    #pragma unroll
    for (int i = 0; i < 4; ++i)
        #pragma unroll
        for (int r = 0; r < 4; ++r) {
            float s = __expf(acc[i][0][r] * INV_TEMP)
                    + __expf(acc[i][1][r] * INV_TEMP)
                    + __expf(acc[i][2][r] * INV_TEMP)
                    + __expf(acc[i][3][r] * INV_TEMP);
            s += __shfl_xor(s, 1);
            s += __shfl_xor(s, 2);
            s += __shfl_xor(s, 4);
            s += __shfl_xor(s, 8);
            if (l16 == 0)
                red[wc * 128 + wr * 64 + i * 16 + quad * 4 + r] = s;
        }
    __syncthreads();

    if (tid < 128)
        part[(size_t)colblk * NROWS + rowbase + tid] = red[tid] + red[128 + tid];

    // ---- fused rowsum via completion tickets ----------------------------
    __threadfence();                   // writers: push part[] out (agent)
    __syncthreads();                   // all writes fenced before ticket
    __shared__ int swin;
    __shared__ int sdone;
    __shared__ float wsum[2];
    if (tid == 0)
        swin = __hip_atomic_fetch_add(&tickets[rowblk], 1,
                   __ATOMIC_ACQ_REL, __HIP_MEMORY_SCOPE_AGENT);
    __syncthreads();
    if (swin != 63) return;            // not the last colblock for this row

    // winner: per-row total + log - diag (same order as old rowsum_kernel)
    float v = 0.0f;
    if (tid < 128) {
        const int row = rowbase + tid;
        float s = 0.0f;
        #pragma unroll 4
        for (int cb = 0; cb < 64; ++cb)
            s += __hip_atomic_load(&part[(size_t)cb * NROWS + row],
                     __ATOMIC_RELAXED, __HIP_MEMORY_SCOPE_AGENT);
        v = logf(s) - diag[row];
        #pragma unroll
        for (int m = 1; m < 64; m <<= 1) v += __shfl_xor(v, m);
        if ((tid & 63) == 0) wsum[tid >> 6] = v;
    }
    __syncthreads();
    if (tid == 0) {
        __hip_atomic_store(&loss_part[rowblk], wsum[0] + wsum[1],
            __ATOMIC_RELEASE, __HIP_MEMORY_SCOPE_AGENT);
        const int d = __hip_atomic_fetch_add(&tickets[64], 1,
                          __ATOMIC_ACQ_REL, __HIP_MEMORY_SCOPE_AGENT);
        sdone = (d == 63);
    }
    __syncthreads();
    if (!sdone) return;

    // last finisher: final mean (same 64-lane tree as old final_kernel)
    if (tid < 64) {
        float x = __hip_atomic_load(&loss_part[tid],
                      __ATOMIC_RELAXED, __HIP_MEMORY_SCOPE_AGENT);
        #pragma unroll
        for (int m = 1; m < 64; m <<= 1) x += __shfl_xor(x, m);
        if (tid == 0) out[0] = x * (1.0f / NROWS);
    }
}

// ---------------------------------------------------------------------------
extern "C" void kernel_launch(void* const* d_in, const int* in_sizes, int n_in,
                              void* d_out, int out_size, void* d_ws, size_t ws_size,
                              hipStream_t stream)
{
    const float* q = (const float*)d_in[0];
    const float* p = (const float*)d_in[1];

    char* ws = (char*)d_ws;
    unsigned short* qn   = (unsigned short*)ws;                          // 4 MB
    unsigned short* pn   = (unsigned short*)(ws + (size_t)NROWS*DDIM*2); // 4 MB
    float* part      = (float*)(ws + 2*(size_t)NROWS*DDIM*2);            // 2 MB
    float* diag      = part + 64 * (size_t)NROWS;                        // 32 KB
    float* loss_part = diag + NROWS;                                     // 256 B
    int*   tickets   = (int*)(loss_part + 64);                           // 66 ints

    norm_diag_kernel<<<NROWS/4, 256, 0, stream>>>(q, p, qn, pn, diag, tickets);

    dim3 grid(64, 64);   // colblocks x rowblocks (remapped in-kernel)
    simexp_fused_kernel<<<grid, 256, 0, stream>>>(
        qn, pn, part, diag, loss_part, tickets, (float*)d_out);
}

// Round 5
// 139.223 us; speedup vs baseline: 3.2257x; 3.2257x over previous
//
#include <hip/hip_runtime.h>
#include <hip/hip_bf16.h>

#define NROWS 8192
#define DDIM  256
#define INV_TEMP 20.0f   // 1/0.05

typedef __attribute__((ext_vector_type(8))) short bf16x8;
typedef __attribute__((ext_vector_type(4))) float f32x4;

// ---------------------------------------------------------------------------
// Packed fragment-major layout for the bf16 operands:
//   For 16-row tile t (=row>>4) and K-step ks (32 elems = 64B per row),
//   a 1KB block: [quad(0..3)][l16(0..15)][16B], byte addr =
//     (t*8 + ks)*1024 + quad*256 + l16*16 + (elem_in_8)*2
// This is EXACTLY the mfma_f32_16x16x32_bf16 A/B fragment order: lane
// (quad*16+l16) reads its 16B at base+lane*16 -> one coalesced 1KB load
// per wave instruction. R2's fragment-direct idea without its address
// divergence; R1/R3's LDS pipeline without its barriers.
// ---------------------------------------------------------------------------

// Kernel 1: per-row L2-normalize q,p; emit PACKED bf16 copies + fp32 diag.
// One wave per row, 4 rows (4 waves) per block.
// Lane L holds elems 4L..4L+3: ks=L>>3, quad=(L>>1)&3, half=L&1.
// Even/odd lane pairs write adjacent 8B halves of one 16B slot (HW-merged).
__global__ __launch_bounds__(256) void norm_pack_kernel(
    const float* __restrict__ q, const float* __restrict__ p,
    unsigned char* __restrict__ qn, unsigned char* __restrict__ pn,
    float* __restrict__ diag)
{
    const int row  = (blockIdx.x << 2) + (threadIdx.x >> 6);
    const int lane = threadIdx.x & 63;

    const float4 qv = ((const float4*)(q + (size_t)row * DDIM))[lane];
    const float4 pv = ((const float4*)(p + (size_t)row * DDIM))[lane];

    float sq = qv.x*qv.x + qv.y*qv.y + qv.z*qv.z + qv.w*qv.w;
    float sp = pv.x*pv.x + pv.y*pv.y + pv.z*pv.z + pv.w*pv.w;
    #pragma unroll
    for (int m = 1; m < 64; m <<= 1) {
        sq += __shfl_xor(sq, m);
        sp += __shfl_xor(sp, m);
    }
    const float qs = 1.0f / fmaxf(sqrtf(sq), 1e-8f);
    const float ps = 1.0f / fmaxf(sqrtf(sp), 1e-8f);

    const float qx = qv.x*qs, qy = qv.y*qs, qz = qv.z*qs, qw = qv.w*qs;
    const float px = pv.x*ps, py = pv.y*ps, pz = pv.z*ps, pw = pv.w*ps;

    float d = qx*px + qy*py + qz*pz + qw*pw;
    #pragma unroll
    for (int m = 1; m < 64; m <<= 1) d += __shfl_xor(d, m);
    if (lane == 0) diag[row] = d * INV_TEMP;

    union { unsigned short u16[4]; uint2 v; } uq, up;
    {
        __hip_bfloat16 b;
        b = __float2bfloat16(qx); uq.u16[0] = *(unsigned short*)&b;
        b = __float2bfloat16(qy); uq.u16[1] = *(unsigned short*)&b;
        b = __float2bfloat16(qz); uq.u16[2] = *(unsigned short*)&b;
        b = __float2bfloat16(qw); uq.u16[3] = *(unsigned short*)&b;
        b = __float2bfloat16(px); up.u16[0] = *(unsigned short*)&b;
        b = __float2bfloat16(py); up.u16[1] = *(unsigned short*)&b;
        b = __float2bfloat16(pz); up.u16[2] = *(unsigned short*)&b;
        b = __float2bfloat16(pw); up.u16[3] = *(unsigned short*)&b;
    }
    // packed store address for this lane's 8B (4 bf16)
    const size_t pb = (size_t)((row >> 4) * 8 + (lane >> 3)) * 1024
                    + (size_t)(((lane >> 1) & 3) * 256)
                    + (size_t)((row & 15) * 16)
                    + (size_t)((lane & 1) * 8);
    *(uint2*)(qn + pb) = uq.v;
    *(uint2*)(pn + pb) = up.v;
}

// ---------------------------------------------------------------------------
// Kernel 2: fused GEMM + sum-exp. NO LDS staging, NO barriers in main loop.
// Fragments loaded straight from the packed layout: af[i] for A-tile
// (rowbase/16 + wr*4 + i), K-step ks = 16B per lane at
//   packedA + (tile*8+ks)*1024 + lane*16        (coalesced 1KB/wave-instr)
// ks*1024 <= 7KB folds into the 13-bit signed global_load offset -> one
// address register per tile. 2-deep register double-buffer, fully unrolled
// (all indices compile-time, rule #20). Waves free-run; L2-resident operands
// (per-XCD hot set ~1.3MB under the chunked swizzle); wave pairs share
// af/bf addresses -> L1 dedup.
// ---------------------------------------------------------------------------
__global__ __launch_bounds__(256, 3) void simexp_kernel(
    const unsigned char* __restrict__ qn,
    const unsigned char* __restrict__ pn,
    float* __restrict__ part)       // [64 colblocks][8192 rows]
{
    __shared__ float red[256];      // epilogue only

    const int tid  = threadIdx.x;
    const int lane = tid & 63;
    const int w    = tid >> 6;        // wave 0..3
    const int wr   = w >> 1;          // wave row (0..1)
    const int wc   = w & 1;           // wave col (0..1)
    const int quad = lane >> 4;
    const int l16  = lane & 15;

    // ---- XCD-chunked swizzle (bijective on 4096 blocks) ----
    const int L   = blockIdx.y * 64 + blockIdx.x;
    const int xcd = L & 7;
    const int c   = L >> 3;
    const int rowblk = xcd * 8 + (c & 7);
    const int colblk = c >> 3;
    const int rowbase = rowblk * 128;
    const int colbase = colblk * 128;

    // per-tile base pointers (tile = 16 rows): A tiles rowbase/16 + wr*4 + i
    const unsigned char* pa[4];
    const unsigned char* pb[4];
    #pragma unroll
    for (int i = 0; i < 4; ++i) {
        pa[i] = qn + (size_t)((rowbase >> 4) + wr * 4 + i) * 8192 + lane * 16;
        pb[i] = pn + (size_t)((colbase >> 4) + wc * 4 + i) * 8192 + lane * 16;
    }

    f32x4 acc[4][4];
    #pragma unroll
    for (int i = 0; i < 4; ++i)
        #pragma unroll
        for (int j = 0; j < 4; ++j) acc[i][j] = (f32x4)0.0f;

    bf16x8 af[2][4], bf[2][4];

#define LOADF(buf, ks) do {                                             \
        _Pragma("unroll")                                               \
        for (int i = 0; i < 4; ++i) {                                   \
            af[buf][i] = *(const bf16x8*)(pa[i] + (ks) * 1024);         \
            bf[buf][i] = *(const bf16x8*)(pb[i] + (ks) * 1024);         \
        }                                                               \
    } while (0)

    LOADF(0, 0);

    #pragma unroll
    for (int ks = 0; ks < 8; ++ks) {
        if (ks < 7) LOADF((ks + 1) & 1, ks + 1);   // prefetch next K-step
        const int cur = ks & 1;
        #pragma unroll
        for (int i = 0; i < 4; ++i)
            #pragma unroll
            for (int j = 0; j < 4; ++j)
                acc[i][j] = __builtin_amdgcn_mfma_f32_16x16x32_bf16(
                    af[cur][i], bf[cur][j], acc[i][j], 0, 0, 0);
    }
#undef LOADF

    // epilogue ------------------------------------------------------------
    #pragma unroll
    for (int i = 0; i < 4; ++i)
        #pragma unroll
        for (int r = 0; r < 4; ++r) {
            float s = __expf(acc[i][0][r] * INV_TEMP)
                    + __expf(acc[i][1][r] * INV_TEMP)
                    + __expf(acc[i][2][r] * INV_TEMP)
                    + __expf(acc[i][3][r] * INV_TEMP);
            s += __shfl_xor(s, 1);
            s += __shfl_xor(s, 2);
            s += __shfl_xor(s, 4);
            s += __shfl_xor(s, 8);
            if (l16 == 0)
                red[wc * 128 + wr * 64 + i * 16 + quad * 4 + r] = s;
        }
    __syncthreads();

    if (tid < 128)
        part[(size_t)colblk * NROWS + rowbase + tid] = red[tid] + red[128 + tid];
}

// ---------------------------------------------------------------------------
// Kernel 3: per-row total + log - diag, block-partial loss sums.
// ---------------------------------------------------------------------------
__global__ __launch_bounds__(128) void rowsum_kernel(
    const float* __restrict__ part, const float* __restrict__ diag,
    float* __restrict__ loss_part)
{
    const int row = blockIdx.x * 128 + threadIdx.x;
    float s = 0.0f;
    #pragma unroll 4
    for (int cb = 0; cb < 64; ++cb)
        s += part[(size_t)cb * NROWS + row];     // coalesced across threads
    float v = logf(s) - diag[row];

    #pragma unroll
    for (int m = 1; m < 64; m <<= 1) v += __shfl_xor(v, m);
    __shared__ float wsum[2];
    if ((threadIdx.x & 63) == 0) wsum[threadIdx.x >> 6] = v;
    __syncthreads();
    if (threadIdx.x == 0) loss_part[blockIdx.x] = wsum[0] + wsum[1];
}

// ---------------------------------------------------------------------------
// Kernel 4: final mean over 64 block partials. One wave.
// ---------------------------------------------------------------------------
__global__ __launch_bounds__(64) void final_kernel(
    const float* __restrict__ loss_part, float* __restrict__ out)
{
    float v = loss_part[threadIdx.x];
    #pragma unroll
    for (int m = 1; m < 64; m <<= 1) v += __shfl_xor(v, m);
    if (threadIdx.x == 0) out[0] = v * (1.0f / NROWS);
}

// ---------------------------------------------------------------------------
extern "C" void kernel_launch(void* const* d_in, const int* in_sizes, int n_in,
                              void* d_out, int out_size, void* d_ws, size_t ws_size,
                              hipStream_t stream)
{
    const float* q = (const float*)d_in[0];
    const float* p = (const float*)d_in[1];

    char* ws = (char*)d_ws;
    unsigned char* qn = (unsigned char*)ws;                              // 4 MB packed
    unsigned char* pn = (unsigned char*)(ws + (size_t)NROWS*DDIM*2);     // 4 MB packed
    float* part      = (float*)(ws + 2*(size_t)NROWS*DDIM*2);            // 2 MB
    float* diag      = part + 64 * (size_t)NROWS;                        // 32 KB
    float* loss_part = diag + NROWS;                                     // 256 B

    norm_pack_kernel<<<NROWS/4, 256, 0, stream>>>(q, p, qn, pn, diag);

    dim3 grid(64, 64);   // colblocks x rowblocks (remapped in-kernel)
    simexp_kernel<<<grid, 256, 0, stream>>>(qn, pn, part);

    rowsum_kernel<<<64, 128, 0, stream>>>(part, diag, loss_part);
    final_kernel<<<1, 64, 0, stream>>>(loss_part, (float*)d_out);
}

// Round 6
// 131.132 us; speedup vs baseline: 3.4248x; 1.0617x over previous
//
#include <hip/hip_runtime.h>
#include <hip/hip_bf16.h>

#define NROWS 8192
#define DDIM  256
#define INV_TEMP 20.0f   // 1/0.05

typedef __attribute__((ext_vector_type(8))) short bf16x8;
typedef __attribute__((ext_vector_type(4))) float f32x4;

// async global->LDS, 16B per lane. LDS dest = uniform base + lane*16.
__device__ static inline void async16(const void* g, void* l) {
    __builtin_amdgcn_global_load_lds(
        (const __attribute__((address_space(1))) void*)g,
        (__attribute__((address_space(3))) void*)l, 16, 0, 0);
}

// ---------------------------------------------------------------------------
// Kernel 1: per-row L2-normalize q and p (fp32), emit bf16 copies (linear
// row-major), fp32 diag. One wave per row, 4 rows per block. Block 0 zeroes
// the rowsum ticket (stream-ordered before kernel 3; re-zeroed every launch
// so graph replay is safe).
// ---------------------------------------------------------------------------
__global__ __launch_bounds__(256) void norm_diag_kernel(
    const float* __restrict__ q, const float* __restrict__ p,
    unsigned short* __restrict__ qn, unsigned short* __restrict__ pn,
    float* __restrict__ diag, int* __restrict__ tickets)
{
    if (blockIdx.x == 0 && threadIdx.x == 0) tickets[0] = 0;

    const int row  = (blockIdx.x << 2) + (threadIdx.x >> 6);
    const int lane = threadIdx.x & 63;

    const float4 qv = ((const float4*)(q + (size_t)row * DDIM))[lane];
    const float4 pv = ((const float4*)(p + (size_t)row * DDIM))[lane];

    float sq = qv.x*qv.x + qv.y*qv.y + qv.z*qv.z + qv.w*qv.w;
    float sp = pv.x*pv.x + pv.y*pv.y + pv.z*pv.z + pv.w*pv.w;
    #pragma unroll
    for (int m = 1; m < 64; m <<= 1) {
        sq += __shfl_xor(sq, m);
        sp += __shfl_xor(sp, m);
    }
    const float qs = 1.0f / fmaxf(sqrtf(sq), 1e-8f);
    const float ps = 1.0f / fmaxf(sqrtf(sp), 1e-8f);

    const float qx = qv.x*qs, qy = qv.y*qs, qz = qv.z*qs, qw = qv.w*qs;
    const float px = pv.x*ps, py = pv.y*ps, pz = pv.z*ps, pw = pv.w*ps;

    float d = qx*px + qy*py + qz*pz + qw*pw;
    #pragma unroll
    for (int m = 1; m < 64; m <<= 1) d += __shfl_xor(d, m);
    if (lane == 0) diag[row] = d * INV_TEMP;

    union { unsigned short u16[4]; uint2 v; } uq, up;
    {
        __hip_bfloat16 b;
        b = __float2bfloat16(qx); uq.u16[0] = *(unsigned short*)&b;
        b = __float2bfloat16(qy); uq.u16[1] = *(unsigned short*)&b;
        b = __float2bfloat16(qz); uq.u16[2] = *(unsigned short*)&b;
        b = __float2bfloat16(qw); uq.u16[3] = *(unsigned short*)&b;
        b = __float2bfloat16(px); up.u16[0] = *(unsigned short*)&b;
        b = __float2bfloat16(py); up.u16[1] = *(unsigned short*)&b;
        b = __float2bfloat16(pz); up.u16[2] = *(unsigned short*)&b;
        b = __float2bfloat16(pw); up.u16[3] = *(unsigned short*)&b;
    }
    *(uint2*)(qn + (size_t)row * DDIM + lane * 4) = uq.v;
    *(uint2*)(pn + (size_t)row * DDIM + lane * 4) = up.v;
}

// ---------------------------------------------------------------------------
// Kernel 2: fused GEMM + sum-exp, 256x256 tile (2x arithmetic intensity vs
// the 128x128 variant: 256 MB total L2 traffic instead of 512 MB, and 4x
// fewer block prologue/epilogues). 512 threads = 8 waves (2 row x 4 col),
// wave tile 128x64, BK=32 x 8 K-steps. Same PROVEN pipeline as R1/R3:
// 3 LDS buffers (32 KB each: A 16K | B 16K), stage(t) issued at iter t-2,
// raw s_barrier + counted s_waitcnt vmcnt(4) (4 async16 per wave per stage,
// never drained to 0 in-loop). LDS 96 KB -> 1 block/CU, 8 waves.
// ---------------------------------------------------------------------------
__global__ __launch_bounds__(512, 2) void simexp_kernel(
    const unsigned short* __restrict__ qn,
    const unsigned short* __restrict__ pn,
    float* __restrict__ part)       // [32 colblocks][8192 rows]
{
    __shared__ unsigned char lds[3 * 32768];   // 3 x (As 16KB | Bs 16KB)

    const int tid  = threadIdx.x;
    const int lane = tid & 63;
    const int w    = tid >> 6;        // wave 0..7
    const int wr   = w >> 2;          // wave row (0..1): 128 rows each
    const int wc   = w & 3;           // wave col (0..3): 64 cols each
    const int quad = lane >> 4;
    const int l16  = lane & 15;

    // ---- XCD-chunked swizzle (bijective on 1024 blocks) ----
    const int L   = blockIdx.y * 32 + blockIdx.x;
    const int xcd = L & 7;
    const int c   = L >> 3;                     // 0..127
    const int rowblk = xcd * 4 + (c & 3);       // 32 rowblocks, 4 per XCD
    const int colblk = c >> 2;                  // 0..31
    const int rowbase = rowblk * 256;
    const int colbase = colblk * 256;

    // staging: 16 row-tiles of A, 16 col-tiles of B per K-step; wave w
    // stages tiles {2w, 2w+1} of each. lane l -> row (l&15), 16B chunk (l>>4).
    const unsigned short* gA0 = qn + (size_t)(rowbase + (2*w  )*16 + l16) * DDIM + quad * 8;
    const unsigned short* gA1 = qn + (size_t)(rowbase + (2*w+1)*16 + l16) * DDIM + quad * 8;
    const unsigned short* gB0 = pn + (size_t)(colbase + (2*w  )*16 + l16) * DDIM + quad * 8;
    const unsigned short* gB1 = pn + (size_t)(colbase + (2*w+1)*16 + l16) * DDIM + quad * 8;

    f32x4 acc[8][4];
    #pragma unroll
    for (int i = 0; i < 8; ++i)
        #pragma unroll
        for (int j = 0; j < 4; ++j) acc[i][j] = (f32x4)0.0f;

    // 4 async16 per wave per STAGE -> vmcnt granularity of 4 (as in R1).
#define STAGE(buf, ks) do {                                             \
        unsigned char* _b = lds + (buf) * 32768;                        \
        async16(gA0 + (ks) * 32, _b +         (2*w    ) * 1024);        \
        async16(gA1 + (ks) * 32, _b +         (2*w + 1) * 1024);        \
        async16(gB0 + (ks) * 32, _b + 16384 + (2*w    ) * 1024);        \
        async16(gB1 + (ks) * 32, _b + 16384 + (2*w + 1) * 1024);        \
    } while (0)

    STAGE(0, 0);
    STAGE(1, 1);
    asm volatile("s_waitcnt vmcnt(4)" ::: "memory");   // stage(0) landed
    __builtin_amdgcn_s_barrier();
    asm volatile("" ::: "memory");

    #pragma unroll
    for (int ks = 0; ks < 8; ++ks) {
        if (ks < 6) STAGE((ks + 2) % 3, ks + 2);       // issue 2 tiles ahead

        const unsigned char* ba = lds + (ks % 3) * 32768;
        bf16x8 af[8], bf[4];
        #pragma unroll
        for (int i = 0; i < 8; ++i)
            af[i] = *(const bf16x8*)(ba + (wr*8 + i) * 1024 + quad * 256 + l16 * 16);
        #pragma unroll
        for (int j = 0; j < 4; ++j)
            bf[j] = *(const bf16x8*)(ba + 16384 + (wc*4 + j) * 1024 + quad * 256 + l16 * 16);

        #pragma unroll
        for (int i = 0; i < 8; ++i)
            #pragma unroll
            for (int j = 0; j < 4; ++j)
                acc[i][j] = __builtin_amdgcn_mfma_f32_16x16x32_bf16(
                    af[i], bf[j], acc[i][j], 0, 0, 0);

        if (ks < 7) {
            if (ks < 6) { asm volatile("s_waitcnt vmcnt(4)" ::: "memory"); } // stage(ks+1) done
            else        { asm volatile("s_waitcnt vmcnt(0)" ::: "memory"); } // stage(7) done
            __builtin_amdgcn_s_barrier();
            asm volatile("" ::: "memory");
        }
    }
#undef STAGE

    // epilogue ------------------------------------------------------------
    __syncthreads();                   // all ds_reads done; reuse LDS
    float* red = (float*)lds;          // 4 x 256 floats: [wc][256 rows]

    #pragma unroll
    for (int i = 0; i < 8; ++i)
        #pragma unroll
        for (int r = 0; r < 4; ++r) {
            float s = __expf(acc[i][0][r] * INV_TEMP)
                    + __expf(acc[i][1][r] * INV_TEMP)
                    + __expf(acc[i][2][r] * INV_TEMP)
                    + __expf(acc[i][3][r] * INV_TEMP);
            s += __shfl_xor(s, 1);
            s += __shfl_xor(s, 2);
            s += __shfl_xor(s, 4);
            s += __shfl_xor(s, 8);
            if (l16 == 0)
                red[wc * 256 + wr * 128 + i * 16 + quad * 4 + r] = s;
        }
    __syncthreads();

    if (tid < 256)
        part[(size_t)colblk * NROWS + rowbase + tid] =
            red[tid] + red[256 + tid] + red[512 + tid] + red[768 + tid];
}

// ---------------------------------------------------------------------------
// Kernel 3: per-row total + log - diag, block partials, FUSED final mean via
// a 64-block completion ticket (64 agent-scope RMWs ~ 3-5 us << one launch).
// ---------------------------------------------------------------------------
__global__ __launch_bounds__(128) void rowsum_final_kernel(
    const float* __restrict__ part, const float* __restrict__ diag,
    float* __restrict__ loss_part, int* __restrict__ tickets,
    float* __restrict__ out)
{
    const int row = blockIdx.x * 128 + threadIdx.x;
    float s = 0.0f;
    #pragma unroll 4
    for (int cb = 0; cb < 32; ++cb)
        s += part[(size_t)cb * NROWS + row];     // coalesced across threads
    float v = logf(s) - diag[row];

    #pragma unroll
    for (int m = 1; m < 64; m <<= 1) v += __shfl_xor(v, m);
    __shared__ float wsum[2];
    __shared__ int swin;
    if ((threadIdx.x & 63) == 0) wsum[threadIdx.x >> 6] = v;
    __syncthreads();
    if (threadIdx.x == 0) {
        __hip_atomic_store(&loss_part[blockIdx.x], wsum[0] + wsum[1],
            __ATOMIC_RELEASE, __HIP_MEMORY_SCOPE_AGENT);
        swin = __hip_atomic_fetch_add(&tickets[0], 1,
                   __ATOMIC_ACQ_REL, __HIP_MEMORY_SCOPE_AGENT);
    }
    __syncthreads();
    if (swin != 63) return;            // not the last block

    if (threadIdx.x < 64) {
        float x = __hip_atomic_load(&loss_part[threadIdx.x],
                      __ATOMIC_RELAXED, __HIP_MEMORY_SCOPE_AGENT);
        #pragma unroll
        for (int m = 1; m < 64; m <<= 1) x += __shfl_xor(x, m);
        if (threadIdx.x == 0) out[0] = x * (1.0f / NROWS);
    }
}

// ---------------------------------------------------------------------------
extern "C" void kernel_launch(void* const* d_in, const int* in_sizes, int n_in,
                              void* d_out, int out_size, void* d_ws, size_t ws_size,
                              hipStream_t stream)
{
    const float* q = (const float*)d_in[0];
    const float* p = (const float*)d_in[1];

    char* ws = (char*)d_ws;
    unsigned short* qn   = (unsigned short*)ws;                          // 4 MB
    unsigned short* pn   = (unsigned short*)(ws + (size_t)NROWS*DDIM*2); // 4 MB
    float* part      = (float*)(ws + 2*(size_t)NROWS*DDIM*2);            // 1 MB
    float* diag      = part + 32 * (size_t)NROWS;                        // 32 KB
    float* loss_part = diag + NROWS;                                     // 256 B
    int*   tickets   = (int*)(loss_part + 64);

    norm_diag_kernel<<<NROWS/4, 256, 0, stream>>>(q, p, qn, pn, diag, tickets);

    dim3 grid(32, 32);   // colblocks x rowblocks (remapped in-kernel)
    simexp_kernel<<<grid, 512, 0, stream>>>(qn, pn, part);

    rowsum_final_kernel<<<64, 128, 0, stream>>>(part, diag, loss_part,
                                                tickets, (float*)d_out);
}